// Round 13
// baseline (46.606 us; speedup 1.0000x reference)
//
#include <hip/hip_runtime.h>
#include <hip/hip_bf16.h>

// ROUND 13 = DIAGNOSTIC. R12 fused kernel + runtime rep loop (rep=6) so the
// fused kernel's dispatch (~cold + 5*warm) exceeds the ~40us harness fills and
// surfaces in rocprof top-5 with readable warm counters. Passes are idempotent
// (barrier at rep top; output rewritten identically). real warm cost =
// (dur - cold) / 5; decision table pre-committed in the journal.

#define B_     64
#define M_     127
#define TWOB_  128

using bf16x8 = __attribute__((ext_vector_type(8))) short;
using f32x4  = __attribute__((ext_vector_type(4))) float;

__device__ inline short f2bf(float x) {
    __hip_bfloat16 h = __float2bfloat16(x);
    return *reinterpret_cast<short*>(&h);
}

__device__ inline int wave_lb(const int* __restrict__ arr, int n, int target, int lane) {
    int a = 0, w = n;
    while (w > 64) {
        int step = (w + 63) >> 6;
        int off  = lane * step;
        bool inr = (off < w);
        int p    = a + (inr ? off : 0);
        int v    = (inr && p < n) ? arr[p] : 0x7fffffff;
        unsigned long long mask = __ballot(v < target);
        int c = __popcll(mask);
        int a2 = (c > 0) ? (a + (c - 1) * step + 1) : a;
        int U  = (c * step < w) ? (a + c * step) : (a + w);
        a = a2;
        w = U - a2;
        if (w < 0) w = 0;
    }
    bool lt = (lane < w) && (a + lane < n) && (arr[a + lane] < target);
    return a + __popcll(__ballot(lt));
}

__global__ __launch_bounds__(256, 4) void fdlt_fused(
    const float* __restrict__ psiHat,
    const float* __restrict__ Cm,
    const float* __restrict__ XFc,
    const float* __restrict__ XFs,
    const float* __restrict__ Dval,
    const int*   __restrict__ Drow,
    const int*   __restrict__ Dcol,
    int nnz,
    float* __restrict__ out,
    int rep)
{
    __shared__ short EmL[B_ * TWOB_];
    __shared__ short As [B_ * TWOB_];
    __shared__ short Dmb[B_ * B_];

    const int bid  = blockIdx.x;
    const int xcd  = bid & 7;
    const int rest = bid >> 3;
    const int m    = xcd + ((rest & 15) << 3);
    const int tile = rest >> 4;
    if (m >= M_) return;
    const int b0 = tile * 64;
    const int t  = threadIdx.x;

    const int lane = t & 63;
    const int w    = t >> 6;
    const int lr   = lane & 15;
    const int lg   = lane >> 4;

    for (int r = 0; r < rep; ++r) {
        __syncthreads();                         // prev rep's ph3 reads done

        // ---- ph0a: issue psiHat loads early
        f32x4 pre[8];
        #pragma unroll
        for (int j = 0; j < 4; ++j) {
            int unit = t + j * 256;
            int row  = unit >> 4;
            int u    = unit & 15;
            const float* src = psiHat + ((size_t)(b0 + row) * M_ + m) * TWOB_ + u * 8;
            pre[2 * j]     = *reinterpret_cast<const f32x4*>(src);
            pre[2 * j + 1] = *reinterpret_cast<const f32x4*>(src + 4);
        }

        // ---- ph0b: zero Dmb
        {
            uint4 z = make_uint4(0, 0, 0, 0);
            uint4* p = reinterpret_cast<uint4*>(Dmb);
            p[t] = z;
            p[t + 256] = z;
        }

        // ---- ph0c: COO segment via wave-parallel lower_bound
        const int lo = wave_lb(Drow, nnz, m * B_, lane);
        const int hi = wave_lb(Drow, nnz, (m + 1) * B_, lane);

        // ---- ph0d: issue scatter loads
        int   rr[9], cc[9];
        float vv[9];
        bool  ok[9];
        #pragma unroll
        for (int j = 0; j < 9; ++j) {
            int i  = lo + t + j * 256;
            ok[j]  = (i < hi);
            int ic = i < nnz ? i : (nnz - 1);
            rr[j] = Drow[ic];
            cc[j] = Dcol[ic];
            vv[j] = Dval[ic];
        }

        // ---- ph0e: write As
        #pragma unroll
        for (int j = 0; j < 4; ++j) {
            int unit = t + j * 256;
            int row  = unit >> 4;
            int u    = unit & 15;
            bf16x8 s;
            s[0] = f2bf(pre[2*j][0]); s[1] = f2bf(pre[2*j][1]);
            s[2] = f2bf(pre[2*j][2]); s[3] = f2bf(pre[2*j][3]);
            s[4] = f2bf(pre[2*j+1][0]); s[5] = f2bf(pre[2*j+1][1]);
            s[6] = f2bf(pre[2*j+1][2]); s[7] = f2bf(pre[2*j+1][3]);
            *reinterpret_cast<bf16x8*>(As + row * TWOB_ + ((u ^ (row & 15)) << 3)) = s;
        }
        __syncthreads();                         // B1

        // ---- ph1: scatter into Dmb
        #pragma unroll
        for (int j = 0; j < 9; ++j) {
            if (ok[j]) {
                int l = rr[j] - m * B_;
                int n = cc[j] - m * TWOB_;
                int u = n >> 3;
                Dmb[l * B_ + (((u ^ (l & 7)) << 3) | (n & 7))] = f2bf(vv[j]);
            }
        }
        __syncthreads();                         // B2

        // ---- ph2: build EmL via MFMA
        const float* __restrict__ XF = (m & 1) ? XFc : XFs;
        const float cm = Cm[m];

        f32x4 bacc[2][4];
        #pragma unroll
        for (int kt2 = 0; kt2 < 2; ++kt2)
            #pragma unroll
            for (int lt = 0; lt < 4; ++lt) bacc[kt2][lt] = (f32x4){0.f, 0.f, 0.f, 0.f};

        #pragma unroll
        for (int ks = 0; ks < 2; ++ks) {
            bf16x8 af[2];
            #pragma unroll
            for (int kt2 = 0; kt2 < 2; ++kt2) {
                const float* ap = XF + (size_t)((w * 2 + kt2) * 16 + lr) * TWOB_ + ks * 32 + lg * 8;
                f32x4 p0 = *reinterpret_cast<const f32x4*>(ap);
                f32x4 p1 = *reinterpret_cast<const f32x4*>(ap + 4);
                af[kt2][0] = f2bf(p0[0]); af[kt2][1] = f2bf(p0[1]);
                af[kt2][2] = f2bf(p0[2]); af[kt2][3] = f2bf(p0[3]);
                af[kt2][4] = f2bf(p1[0]); af[kt2][5] = f2bf(p1[1]);
                af[kt2][6] = f2bf(p1[2]); af[kt2][7] = f2bf(p1[3]);
            }
            #pragma unroll
            for (int lt = 0; lt < 4; ++lt) {
                int l = lt * 16 + lr;
                int g = ks * 4 + lg;
                bf16x8 bfr = *reinterpret_cast<const bf16x8*>(Dmb + l * B_ + ((g ^ (l & 7)) << 3));
                bacc[0][lt] = __builtin_amdgcn_mfma_f32_16x16x32_bf16(af[0], bfr, bacc[0][lt], 0, 0, 0);
                bacc[1][lt] = __builtin_amdgcn_mfma_f32_16x16x32_bf16(af[1], bfr, bacc[1][lt], 0, 0, 0);
            }
        }
        #pragma unroll
        for (int kt2 = 0; kt2 < 2; ++kt2) {
            #pragma unroll
            for (int lt = 0; lt < 4; ++lt) {
                int l  = lt * 16 + lr;
                int k0 = (w * 2 + kt2) * 16 + lg * 4;
                unsigned short h0 = (unsigned short)f2bf(cm * bacc[kt2][lt][0]);
                unsigned short h1 = (unsigned short)f2bf(cm * bacc[kt2][lt][1]);
                unsigned short h2 = (unsigned short)f2bf(cm * bacc[kt2][lt][2]);
                unsigned short h3 = (unsigned short)f2bf(cm * bacc[kt2][lt][3]);
                uint2 pack;
                pack.x = (unsigned)h0 | ((unsigned)h1 << 16);
                pack.y = (unsigned)h2 | ((unsigned)h3 << 16);
                int u    = k0 >> 3;
                int half = (k0 >> 2) & 1;
                *reinterpret_cast<uint2*>(EmL + l * TWOB_ + ((u ^ (l & 15)) << 3) + (half << 2)) = pack;
            }
        }
        __syncthreads();                         // B3

        // ---- ph3: main MFMA
        f32x4 acc[4];
        #pragma unroll
        for (int nt = 0; nt < 4; ++nt) acc[nt] = (f32x4){0.f, 0.f, 0.f, 0.f};

        #pragma unroll
        for (int ks = 0; ks < 4; ++ks) {
            int l  = w * 16 + lr;
            int g2 = ks * 4 + lg;
            bf16x8 af = *reinterpret_cast<const bf16x8*>(EmL + l * TWOB_ + ((g2 ^ lr) << 3));
            #pragma unroll
            for (int nt = 0; nt < 4; ++nt) {
                int row = nt * 16 + lr;
                bf16x8 bfr = *reinterpret_cast<const bf16x8*>(As + row * TWOB_ + ((g2 ^ lr) << 3));
                acc[nt] = __builtin_amdgcn_mfma_f32_16x16x32_bf16(af, bfr, acc[nt], 0, 0, 0);
            }
        }

        #pragma unroll
        for (int nt = 0; nt < 4; ++nt) {
            int b = b0 + nt * 16 + lr;
            float4 v;
            v.x = acc[nt][0]; v.y = acc[nt][1]; v.z = acc[nt][2]; v.w = acc[nt][3];
            *reinterpret_cast<float4*>(out + ((size_t)b * M_ + m) * B_ + w * 16 + lg * 4) = v;
        }
    }
}

extern "C" void kernel_launch(void* const* d_in, const int* in_sizes, int n_in,
                              void* d_out, int out_size, void* d_ws, size_t ws_size,
                              hipStream_t stream) {
    const float* psiHat = (const float*)d_in[0];
    const float* Cm     = (const float*)d_in[1];
    const float* XFc    = (const float*)d_in[2];
    const float* XFs    = (const float*)d_in[3];
    const float* Dval   = (const float*)d_in[4];
    const int*   Drow   = (const int*)d_in[5];
    const int*   Dcol   = (const int*)d_in[6];
    const int nnz = in_sizes[4];

    fdlt_fused<<<dim3(1024), dim3(256), 0, stream>>>(
        psiHat, Cm, XFc, XFs, Dval, Drow, Dcol, nnz, (float*)d_out, 6);
}

// Round 14
// 41.121 us; speedup vs baseline: 1.1334x; 1.1334x over previous
//
#include <hip/hip_runtime.h>
#include <hip/hip_bf16.h>

// FDLT single-launch producer/consumer (round 14).
// out[b,m,l] = sum_k psiHat[b,m,k] * Em[m][k][l],
//   Em[m][k][l] = Cm[m] * sum_{n<64} XF_sel(m)[k][n] * Dm[m][l][n]
// Grid 1151 = 127 builders (bid=m, XCD m%8) + 1024 gemm blocks.
// Builder: lb -> scatter Dmb -> build-MFMA vs XF -> Em[m] (16KB, swizzled
//   units) to global (XCD-local L2) -> threadfence -> flag[m]=TOKEN (release).
// Gemm: issue psiHat loads AT T=0 (33MB stream overlaps the build) -> As
//   (bf16, swizzled) -> acquire-spin flag[m] -> af direct from L2-hot Em ->
//   16 MFMA -> float4 out. 16KB LDS, short path, all 1151 blocks co-resident.
// Replay-safe: Em rewritten with identical bytes each launch; stale TOKEN at
// worst skips a spin on identical data. absmax bit-identical to R12.

#define B_     64
#define M_     127
#define TWOB_  128
#define TOKEN  0x7A3B11C5u

using bf16x8 = __attribute__((ext_vector_type(8))) short;  // 8 bf16 (4 VGPR)
using f32x4  = __attribute__((ext_vector_type(4))) float;

__device__ inline short f2bf(float x) {
    __hip_bfloat16 h = __float2bfloat16(x);
    return *reinterpret_cast<short*>(&h);
}

__device__ inline int wave_lb(const int* __restrict__ arr, int n, int target, int lane) {
    int a = 0, w = n;
    while (w > 64) {
        int step = (w + 63) >> 6;
        int off  = lane * step;
        bool inr = (off < w);
        int p    = a + (inr ? off : 0);
        int v    = (inr && p < n) ? arr[p] : 0x7fffffff;
        unsigned long long mask = __ballot(v < target);
        int c = __popcll(mask);
        int a2 = (c > 0) ? (a + (c - 1) * step + 1) : a;
        int U  = (c * step < w) ? (a + c * step) : (a + w);
        a = a2;
        w = U - a2;
        if (w < 0) w = 0;
    }
    bool lt = (lane < w) && (a + lane < n) && (arr[a + lane] < target);
    return a + __popcll(__ballot(lt));
}

__global__ __launch_bounds__(256) void fdlt_pc(
    const float* __restrict__ psiHat,
    const float* __restrict__ Cm,
    const float* __restrict__ XFc,
    const float* __restrict__ XFs,
    const float* __restrict__ Dval,
    const int*   __restrict__ Drow,
    const int*   __restrict__ Dcol,
    int nnz,
    short* __restrict__ Em,            // bf16 bits [m][l][k], unit-swizzled
    unsigned int* __restrict__ flags,  // [127]
    float* __restrict__ out)
{
    __shared__ short ShMem[B_ * TWOB_];   // 16 KB (builder: Dmb 8KB; gemm: As)

    const int bid  = blockIdx.x;
    const int t    = threadIdx.x;
    const int lane = t & 63;
    const int w    = t >> 6;
    const int lr   = lane & 15;
    const int lg   = lane >> 4;

    if (bid < M_) {
        // ================= builder for m = bid (XCD = m%8) =================
        short* Dmb = ShMem;               // 8 KB used
        const int m = bid;

        {   // zero Dmb
            uint4 z = make_uint4(0, 0, 0, 0);
            uint4* p = reinterpret_cast<uint4*>(Dmb);
            p[t] = z;
            p[t + 256] = z;
        }
        const int lo = wave_lb(Drow, nnz, m * B_, lane);
        const int hi = wave_lb(Drow, nnz, (m + 1) * B_, lane);

        int   rr[9], cc[9];
        float vv[9];
        bool  ok[9];
        #pragma unroll
        for (int j = 0; j < 9; ++j) {
            int i  = lo + t + j * 256;
            ok[j]  = (i < hi);
            int ic = i < nnz ? i : (nnz - 1);
            rr[j] = Drow[ic];
            cc[j] = Dcol[ic];
            vv[j] = Dval[ic];
        }
        __syncthreads();                  // zero visible
        #pragma unroll
        for (int j = 0; j < 9; ++j) {
            if (ok[j]) {
                int l = rr[j] - m * B_;
                int n = cc[j] - m * TWOB_;
                int u = n >> 3;
                Dmb[l * B_ + (((u ^ (l & 7)) << 3) | (n & 7))] = f2bf(vv[j]);
            }
        }
        __syncthreads();                  // scattered

        const float* __restrict__ XF = (m & 1) ? XFc : XFs;
        const float cm = Cm[m];

        f32x4 bacc[2][4];
        #pragma unroll
        for (int kt2 = 0; kt2 < 2; ++kt2)
            #pragma unroll
            for (int lt = 0; lt < 4; ++lt) bacc[kt2][lt] = (f32x4){0.f, 0.f, 0.f, 0.f};

        #pragma unroll
        for (int ks = 0; ks < 2; ++ks) {
            bf16x8 af[2];
            #pragma unroll
            for (int kt2 = 0; kt2 < 2; ++kt2) {
                const float* ap = XF + (size_t)((w * 2 + kt2) * 16 + lr) * TWOB_ + ks * 32 + lg * 8;
                f32x4 p0 = *reinterpret_cast<const f32x4*>(ap);
                f32x4 p1 = *reinterpret_cast<const f32x4*>(ap + 4);
                af[kt2][0] = f2bf(p0[0]); af[kt2][1] = f2bf(p0[1]);
                af[kt2][2] = f2bf(p0[2]); af[kt2][3] = f2bf(p0[3]);
                af[kt2][4] = f2bf(p1[0]); af[kt2][5] = f2bf(p1[1]);
                af[kt2][6] = f2bf(p1[2]); af[kt2][7] = f2bf(p1[3]);
            }
            #pragma unroll
            for (int lt = 0; lt < 4; ++lt) {
                int l = lt * 16 + lr;
                int g = ks * 4 + lg;
                bf16x8 bfr = *reinterpret_cast<const bf16x8*>(Dmb + l * B_ + ((g ^ (l & 7)) << 3));
                bacc[0][lt] = __builtin_amdgcn_mfma_f32_16x16x32_bf16(af[0], bfr, bacc[0][lt], 0, 0, 0);
                bacc[1][lt] = __builtin_amdgcn_mfma_f32_16x16x32_bf16(af[1], bfr, bacc[1][lt], 0, 0, 0);
            }
        }
        // write Em[m] to global, same unit swizzle u ^= (l&15) as consumer read
        #pragma unroll
        for (int kt2 = 0; kt2 < 2; ++kt2) {
            #pragma unroll
            for (int lt = 0; lt < 4; ++lt) {
                int l  = lt * 16 + lr;
                int k0 = (w * 2 + kt2) * 16 + lg * 4;
                unsigned short h0 = (unsigned short)f2bf(cm * bacc[kt2][lt][0]);
                unsigned short h1 = (unsigned short)f2bf(cm * bacc[kt2][lt][1]);
                unsigned short h2 = (unsigned short)f2bf(cm * bacc[kt2][lt][2]);
                unsigned short h3 = (unsigned short)f2bf(cm * bacc[kt2][lt][3]);
                uint2 pack;
                pack.x = (unsigned)h0 | ((unsigned)h1 << 16);
                pack.y = (unsigned)h2 | ((unsigned)h3 << 16);
                int u    = k0 >> 3;
                int half = (k0 >> 2) & 1;
                *reinterpret_cast<uint2*>(
                    Em + (size_t)(m * B_ + l) * TWOB_ + ((u ^ (l & 15)) << 3) + (half << 2)) = pack;
            }
        }
        __threadfence();                  // Em visible device-wide
        __syncthreads();                  // all threads' stores fenced
        if (t == 0)
            __hip_atomic_store(flags + m, TOKEN, __ATOMIC_RELEASE, __HIP_MEMORY_SCOPE_AGENT);
    } else {
        // ================= gemm block =================
        short* As = ShMem;                // 16 KB
        const int j    = bid - M_;
        const int px   = bid & 7;                      // physical XCD
        const int m    = px + (((j >> 3) & 15) << 3);  // same-XCD as builder m
        const int tile = j >> 7;
        if (m >= M_) return;                           // 8 guard blocks
        const int b0 = tile * 64;

        // issue all psiHat loads NOW (overlaps builder latency chip-wide)
        f32x4 pre[8];
        #pragma unroll
        for (int jj = 0; jj < 4; ++jj) {
            int unit = t + jj * 256;
            int row  = unit >> 4;
            int u    = unit & 15;
            const float* src = psiHat + ((size_t)(b0 + row) * M_ + m) * TWOB_ + u * 8;
            pre[2 * jj]     = *reinterpret_cast<const f32x4*>(src);
            pre[2 * jj + 1] = *reinterpret_cast<const f32x4*>(src + 4);
        }
        // As write (vmcnt-gated), swizzle u ^= (row&15)
        #pragma unroll
        for (int jj = 0; jj < 4; ++jj) {
            int unit = t + jj * 256;
            int row  = unit >> 4;
            int u    = unit & 15;
            bf16x8 s;
            s[0] = f2bf(pre[2*jj][0]); s[1] = f2bf(pre[2*jj][1]);
            s[2] = f2bf(pre[2*jj][2]); s[3] = f2bf(pre[2*jj][3]);
            s[4] = f2bf(pre[2*jj+1][0]); s[5] = f2bf(pre[2*jj+1][1]);
            s[6] = f2bf(pre[2*jj+1][2]); s[7] = f2bf(pre[2*jj+1][3]);
            *reinterpret_cast<bf16x8*>(As + row * TWOB_ + ((u ^ (row & 15)) << 3)) = s;
        }
        // acquire-spin on builder flag (usually already set)
        if (t == 0) {
            while (__hip_atomic_load(flags + m, __ATOMIC_ACQUIRE, __HIP_MEMORY_SCOPE_AGENT) != TOKEN) {
                __builtin_amdgcn_s_sleep(8);
            }
        }
        __syncthreads();                  // As ready AND flag observed

        // af from global Em (XCD-local L2), swizzled units
        const short* __restrict__ ebase = Em + (size_t)(m * B_ + w * 16 + lr) * TWOB_;
        bf16x8 af[4];
        #pragma unroll
        for (int ks = 0; ks < 4; ++ks)
            af[ks] = *reinterpret_cast<const bf16x8*>(ebase + (((ks * 4 + lg) ^ lr) << 3));

        f32x4 acc[4];
        #pragma unroll
        for (int nt = 0; nt < 4; ++nt) acc[nt] = (f32x4){0.f, 0.f, 0.f, 0.f};

        #pragma unroll
        for (int ks = 0; ks < 4; ++ks) {
            int g2 = ks * 4 + lg;
            #pragma unroll
            for (int nt = 0; nt < 4; ++nt) {
                int row = nt * 16 + lr;
                bf16x8 bfr = *reinterpret_cast<const bf16x8*>(As + row * TWOB_ + ((g2 ^ lr) << 3));
                acc[nt] = __builtin_amdgcn_mfma_f32_16x16x32_bf16(af[ks], bfr, acc[nt], 0, 0, 0);
            }
        }

        #pragma unroll
        for (int nt = 0; nt < 4; ++nt) {
            int b = b0 + nt * 16 + lr;
            float4 v;
            v.x = acc[nt][0]; v.y = acc[nt][1]; v.z = acc[nt][2]; v.w = acc[nt][3];
            *reinterpret_cast<float4*>(out + ((size_t)b * M_ + m) * B_ + w * 16 + lg * 4) = v;
        }
    }
}

extern "C" void kernel_launch(void* const* d_in, const int* in_sizes, int n_in,
                              void* d_out, int out_size, void* d_ws, size_t ws_size,
                              hipStream_t stream) {
    const float* psiHat = (const float*)d_in[0];
    const float* Cm     = (const float*)d_in[1];
    const float* XFc    = (const float*)d_in[2];
    const float* XFs    = (const float*)d_in[3];
    const float* Dval   = (const float*)d_in[4];
    const int*   Drow   = (const int*)d_in[5];
    const int*   Dcol   = (const int*)d_in[6];
    const int nnz = in_sizes[4];

    // ws: [0, 2,080,768) Em bf16-bits; then flags[127] (uint).
    short* Em = (short*)d_ws;
    unsigned int* flags = (unsigned int*)((char*)d_ws + (size_t)M_ * B_ * TWOB_ * sizeof(short));

    fdlt_pc<<<dim3(M_ + 1024), dim3(256), 0, stream>>>(
        psiHat, Cm, XFc, XFs, Dval, Drow, Dcol, nnz, Em, flags, (float*)d_out);
}

// Round 15
// 20.282 us; speedup vs baseline: 2.2979x; 2.0274x over previous
//
#include <hip/hip_runtime.h>
#include <hip/hip_bf16.h>

// FDLT fused single-kernel (round 15) = R12 (best 21.5us) +
//  (1) NON-TEMPORAL psiHat loads + out stores (both are pure streams; keep
//      L2 for COO/XF/Em and stop allocate/evict churn on 50MB of dead lines)
//  (2) XF loads hoisted into ph0 (last cold loads left on a post-barrier path)
// Phases: ph0 psiHat-nt + XF loads | zero Dmb | wave-lb | scatter loads |
//         As write;  B1;  scatter->Dmb;  B2;  build EmL via MFMA;  B3;
//         main MFMA -> nt float4 out.  Arithmetic bit-identical to R12.

#define B_     64
#define M_     127
#define TWOB_  128

using bf16x8 = __attribute__((ext_vector_type(8))) short;  // 8 bf16 (4 VGPR)
using f32x4  = __attribute__((ext_vector_type(4))) float;

__device__ inline short f2bf(float x) {
    __hip_bfloat16 h = __float2bfloat16(x);
    return *reinterpret_cast<short*>(&h);
}

__device__ inline int wave_lb(const int* __restrict__ arr, int n, int target, int lane) {
    int a = 0, w = n;
    while (w > 64) {
        int step = (w + 63) >> 6;
        int off  = lane * step;
        bool inr = (off < w);
        int p    = a + (inr ? off : 0);
        int v    = (inr && p < n) ? arr[p] : 0x7fffffff;
        unsigned long long mask = __ballot(v < target);
        int c = __popcll(mask);
        int a2 = (c > 0) ? (a + (c - 1) * step + 1) : a;
        int U  = (c * step < w) ? (a + c * step) : (a + w);
        a = a2;
        w = U - a2;
        if (w < 0) w = 0;
    }
    bool lt = (lane < w) && (a + lane < n) && (arr[a + lane] < target);
    return a + __popcll(__ballot(lt));
}

__global__ __launch_bounds__(256, 4) void fdlt_fused(
    const float* __restrict__ psiHat,
    const float* __restrict__ Cm,
    const float* __restrict__ XFc,
    const float* __restrict__ XFs,
    const float* __restrict__ Dval,
    const int*   __restrict__ Drow,
    const int*   __restrict__ Dcol,
    int nnz,
    float* __restrict__ out)
{
    __shared__ short EmL[B_ * TWOB_];   // 16 KB, ph2 -> ph3
    __shared__ short As [B_ * TWOB_];   // 16 KB, ph0 -> ph3
    __shared__ short Dmb[B_ * B_];      //  8 KB, ph1 -> ph2

    const int bid  = blockIdx.x;
    const int xcd  = bid & 7;
    const int rest = bid >> 3;
    const int m    = xcd + ((rest & 15) << 3);   // 16 m's per XCD (L2 locality)
    const int tile = rest >> 4;
    if (m >= M_) return;                         // 8 guard blocks, uniform exit
    const int b0 = tile * 64;
    const int t  = threadIdx.x;

    const int lane = t & 63;
    const int w    = t >> 6;
    const int lr   = lane & 15;
    const int lg   = lane >> 4;

    // ---- ph0a: issue psiHat loads early, NON-TEMPORAL (pure stream)
    f32x4 pre[8];
    #pragma unroll
    for (int j = 0; j < 4; ++j) {
        int unit = t + j * 256;                  // 1024 16B-units of As
        int row  = unit >> 4;                    // b-row
        int u    = unit & 15;
        const float* src = psiHat + ((size_t)(b0 + row) * M_ + m) * TWOB_ + u * 8;
        pre[2 * j]     = __builtin_nontemporal_load(reinterpret_cast<const f32x4*>(src));
        pre[2 * j + 1] = __builtin_nontemporal_load(reinterpret_cast<const f32x4*>(src + 4));
    }

    // ---- ph0a': hoist XF loads (consumed in ph2; keep cached — reused 8x)
    const float* __restrict__ XF = (m & 1) ? XFc : XFs;
    f32x4 xfp[2][2][2];                          // [ks][kt2][pair]
    #pragma unroll
    for (int ks = 0; ks < 2; ++ks)
        #pragma unroll
        for (int kt2 = 0; kt2 < 2; ++kt2) {
            const float* ap = XF + (size_t)((w * 2 + kt2) * 16 + lr) * TWOB_ + ks * 32 + lg * 8;
            xfp[ks][kt2][0] = *reinterpret_cast<const f32x4*>(ap);
            xfp[ks][kt2][1] = *reinterpret_cast<const f32x4*>(ap + 4);
        }

    // ---- ph0b: zero Dmb (512 uint4, 2/thread)
    {
        uint4 z = make_uint4(0, 0, 0, 0);
        uint4* p = reinterpret_cast<uint4*>(Dmb);
        p[t] = z;
        p[t + 256] = z;
    }

    // ---- ph0c: COO segment via wave-parallel lower_bound
    const int lo = wave_lb(Drow, nnz, m * B_, lane);
    const int hi = wave_lb(Drow, nnz, (m + 1) * B_, lane);

    // ---- ph0d: issue scatter loads (all up-front, clamped, predicated use)
    int   rr[9], cc[9];
    float vv[9];
    bool  ok[9];
    #pragma unroll
    for (int j = 0; j < 9; ++j) {                // max segment 2304 <= 9*256
        int i  = lo + t + j * 256;
        ok[j]  = (i < hi);
        int ic = i < nnz ? i : (nnz - 1);
        rr[j] = Drow[ic];
        cc[j] = Dcol[ic];
        vv[j] = Dval[ic];
    }

    // ---- ph0e: write As (waits psiHat vmcnt; scatter loads stay in flight)
    #pragma unroll
    for (int j = 0; j < 4; ++j) {
        int unit = t + j * 256;
        int row  = unit >> 4;
        int u    = unit & 15;
        bf16x8 s;
        s[0] = f2bf(pre[2*j][0]); s[1] = f2bf(pre[2*j][1]);
        s[2] = f2bf(pre[2*j][2]); s[3] = f2bf(pre[2*j][3]);
        s[4] = f2bf(pre[2*j+1][0]); s[5] = f2bf(pre[2*j+1][1]);
        s[6] = f2bf(pre[2*j+1][2]); s[7] = f2bf(pre[2*j+1][3]);
        *reinterpret_cast<bf16x8*>(As + row * TWOB_ + ((u ^ (row & 15)) << 3)) = s;
    }
    __syncthreads();                             // B1: Dmb zero visible

    // ---- ph1: scatter into Dmb, swizzle u ^= (l&7) (row = 64 shorts = 128B)
    #pragma unroll
    for (int j = 0; j < 9; ++j) {
        if (ok[j]) {
            int l = rr[j] - m * B_;
            int n = cc[j] - m * TWOB_;
            int u = n >> 3;
            Dmb[l * B_ + (((u ^ (l & 7)) << 3) | (n & 7))] = f2bf(vv[j]);
        }
    }
    __syncthreads();                             // B2: Dmb scattered

    // ---- ph2: build EmL = cm * Dm[64x64] @ XF[128x64]^T via MFMA.
    const float cm = Cm[m];

    f32x4 bacc[2][4];
    #pragma unroll
    for (int kt2 = 0; kt2 < 2; ++kt2)
        #pragma unroll
        for (int lt = 0; lt < 4; ++lt) bacc[kt2][lt] = (f32x4){0.f, 0.f, 0.f, 0.f};

    #pragma unroll
    for (int ks = 0; ks < 2; ++ks) {             // n-halves of 32
        bf16x8 af[2];
        #pragma unroll
        for (int kt2 = 0; kt2 < 2; ++kt2) {      // cvt hoisted XF regs
            af[kt2][0] = f2bf(xfp[ks][kt2][0][0]); af[kt2][1] = f2bf(xfp[ks][kt2][0][1]);
            af[kt2][2] = f2bf(xfp[ks][kt2][0][2]); af[kt2][3] = f2bf(xfp[ks][kt2][0][3]);
            af[kt2][4] = f2bf(xfp[ks][kt2][1][0]); af[kt2][5] = f2bf(xfp[ks][kt2][1][1]);
            af[kt2][6] = f2bf(xfp[ks][kt2][1][2]); af[kt2][7] = f2bf(xfp[ks][kt2][1][3]);
        }
        #pragma unroll
        for (int lt = 0; lt < 4; ++lt) {         // B: Dmb col l = lt*16+lr
            int l = lt * 16 + lr;
            int g = ks * 4 + lg;
            bf16x8 bfr = *reinterpret_cast<const bf16x8*>(Dmb + l * B_ + ((g ^ (l & 7)) << 3));
            bacc[0][lt] = __builtin_amdgcn_mfma_f32_16x16x32_bf16(af[0], bfr, bacc[0][lt], 0, 0, 0);
            bacc[1][lt] = __builtin_amdgcn_mfma_f32_16x16x32_bf16(af[1], bfr, bacc[1][lt], 0, 0, 0);
        }
    }
    // write EmL rows l, unit swizzle u ^= (l&15); lane: l = lt*16+lr (D col),
    // k = (2w+kt2)*16 + lg*4 + r (D row) -> uint2 (8B half of a 16B unit)
    #pragma unroll
    for (int kt2 = 0; kt2 < 2; ++kt2) {
        #pragma unroll
        for (int lt = 0; lt < 4; ++lt) {
            int l  = lt * 16 + lr;
            int k0 = (w * 2 + kt2) * 16 + lg * 4;
            unsigned short h0 = (unsigned short)f2bf(cm * bacc[kt2][lt][0]);
            unsigned short h1 = (unsigned short)f2bf(cm * bacc[kt2][lt][1]);
            unsigned short h2 = (unsigned short)f2bf(cm * bacc[kt2][lt][2]);
            unsigned short h3 = (unsigned short)f2bf(cm * bacc[kt2][lt][3]);
            uint2 pack;
            pack.x = (unsigned)h0 | ((unsigned)h1 << 16);
            pack.y = (unsigned)h2 | ((unsigned)h3 << 16);
            int u    = k0 >> 3;
            int half = (k0 >> 2) & 1;
            *reinterpret_cast<uint2*>(EmL + l * TWOB_ + ((u ^ (l & 15)) << 3) + (half << 2)) = pack;
        }
    }
    __syncthreads();                             // B3: EmL (and As) ready

    // ---- ph3: out[64l x 64b] = EmL-frags @ As. Wave w: l in [w*16, +16).
    f32x4 acc[4];
    #pragma unroll
    for (int nt = 0; nt < 4; ++nt) acc[nt] = (f32x4){0.f, 0.f, 0.f, 0.f};

    #pragma unroll
    for (int ks = 0; ks < 4; ++ks) {
        int l  = w * 16 + lr;                    // l&15 == lr
        int g2 = ks * 4 + lg;
        bf16x8 af = *reinterpret_cast<const bf16x8*>(EmL + l * TWOB_ + ((g2 ^ lr) << 3));
        #pragma unroll
        for (int nt = 0; nt < 4; ++nt) {
            int row = nt * 16 + lr;              // b-row; row&15 == lr
            bf16x8 bfr = *reinterpret_cast<const bf16x8*>(As + row * TWOB_ + ((g2 ^ lr) << 3));
            acc[nt] = __builtin_amdgcn_mfma_f32_16x16x32_bf16(af, bfr, acc[nt], 0, 0, 0);
        }
    }

    // D: col=lr -> b, row=lg*4+r -> l: nt float4 store (write-once stream)
    #pragma unroll
    for (int nt = 0; nt < 4; ++nt) {
        int b = b0 + nt * 16 + lr;
        f32x4 v = acc[nt];
        __builtin_nontemporal_store(
            v, reinterpret_cast<f32x4*>(out + ((size_t)b * M_ + m) * B_ + w * 16 + lg * 4));
    }
}

extern "C" void kernel_launch(void* const* d_in, const int* in_sizes, int n_in,
                              void* d_out, int out_size, void* d_ws, size_t ws_size,
                              hipStream_t stream) {
    const float* psiHat = (const float*)d_in[0];
    const float* Cm     = (const float*)d_in[1];
    const float* XFc    = (const float*)d_in[2];
    const float* XFs    = (const float*)d_in[3];
    const float* Dval   = (const float*)d_in[4];
    const int*   Drow   = (const int*)d_in[5];
    const int*   Dcol   = (const int*)d_in[6];
    const int nnz = in_sizes[4];

    fdlt_fused<<<dim3(1024), dim3(256), 0, stream>>>(
        psiHat, Cm, XFc, XFs, Dval, Drow, Dcol, nnz, (float*)d_out);
}